// Round 5
// baseline (183.680 us; speedup 1.0000x reference)
//
#include <hip/hip_runtime.h>
#include <math.h>

#define NBINS 1000
#define NDIM 64
#define DIMS_PER_BLOCK 4
#define DIM_GROUPS (NDIM / DIMS_PER_BLOCK)      // 16
#define BLOCK_THREADS 1024
#define ROWS_PER_ITER (BLOCK_THREADS / 2)       // 512 rows per block-iteration
#define ROW_BLOCKS 128                           // %8==0 -> all dim-groups of a row
                                                 // chunk on the same XCD (id=x+128y,
                                                 // XCD=id%8=x%8); chunk working set
                                                 // (512 rows x 256B ~ 128KB x 16
                                                 // concurrent chunks ~ 2MB) fits the
                                                 // 4MB XCD L2 so partial-line reads/
                                                 // writes merge there (R2-validated;
                                                 // R3 broke this window -> 3x traffic)

// zero the log_det region (atomic fallback path only)
__global__ __launch_bounds__(1024) void mg_zero(float* __restrict__ p, int n) {
    int i = blockIdx.x * blockDim.x + threadIdx.x;
    if (i < n) p[i] = 0.0f;
}

// final reduce: log_det[row] = sum over 16 dim-group partials in ws
__global__ __launch_bounds__(256) void mg_reduce(const float* __restrict__ ws,
                                                 float* __restrict__ out, int B) {
    int row = blockIdx.x * blockDim.x + threadIdx.x;
    if (row >= B) return;
    float s = 0.0f;
#pragma unroll
    for (int g = 0; g < DIM_GROUPS; ++g) s += ws[(size_t)g * B + row];
    out[row] = s;
}

// per-dim math on a quad q=(x_i, c_i, x_{i+1}, c_{i+1}).
// exact searchsorted(side='left') fix-up (compares STORED knots, rarely taken)
// + interp + Giles erfinv. MACRO so quads[] stays a direct LDS access.
#define QDIM_MATH(xd_, base_, i_, q_, sc_, php_, ss_, zout_)                      \
    {                                                                             \
        float xd = (xd_);                                                         \
        int i = (i_);                                                             \
        float4 q = (q_);                                                          \
        if (__builtin_expect((xd > q.z && i < NBINS - 2) ||                       \
                             (xd <= q.x && i > 0), 0)) {                          \
            while (xd > q.z && i < NBINS - 2) { ++i; q = quads[(base_) + i]; }    \
            while (xd <= q.x && i > 0) { --i; q = quads[(base_) + i]; }           \
        }                                                                         \
        float slope = (q.w - q.y) * (sc_);                                        \
        float u = fmaf(slope, xd - q.x, q.y);                                     \
        float ph = fmaxf(slope, 1e-12f);                                          \
        u = fminf(fmaxf(u, 1e-6f), 1.0f - 1e-6f);                                 \
        float e1 = fminf(fmaxf(fmaf(2.0f, u, -1.0f), -0.99999f), 0.99999f);       \
        float wv = -0.6931471805599453f *                                         \
                   __builtin_amdgcn_logf(fmaf(-e1, e1, 1.0f));                    \
        float t = wv - 2.5f;                                                      \
        float p = 2.81022636e-08f;                                                \
        p = fmaf(p, t, 3.43273939e-07f);                                          \
        p = fmaf(p, t, -3.5233877e-06f);                                          \
        p = fmaf(p, t, -4.39150654e-06f);                                         \
        p = fmaf(p, t, 0.00021858087f);                                           \
        p = fmaf(p, t, -0.00125372503f);                                          \
        p = fmaf(p, t, -0.00417768164f);                                          \
        p = fmaf(p, t, 0.246640727f);                                             \
        p = fmaf(p, t, 1.50140941f);                                              \
        if (wv >= 5.0f) {                                                         \
            float tq = sqrtf(wv) - 3.0f;                                          \
            float pt = -0.000200214257f;                                          \
            pt = fmaf(pt, tq, 0.000100950558f);                                   \
            pt = fmaf(pt, tq, 0.00134934322f);                                    \
            pt = fmaf(pt, tq, -0.00367342844f);                                   \
            pt = fmaf(pt, tq, 0.00573950773f);                                    \
            pt = fmaf(pt, tq, -0.0076224613f);                                    \
            pt = fmaf(pt, tq, 0.00943887047f);                                    \
            pt = fmaf(pt, tq, 1.00167406f);                                       \
            pt = fmaf(pt, tq, 2.83297682f);                                       \
            p = pt;                                                               \
        }                                                                         \
        float z = 1.4142135623730951f * p * e1; /* |z|<=4.418, ref clamp dead */  \
        (zout_) = z;                                                              \
        (ss_) = fmaf(z, z, (ss_));                                                \
        (php_) *= ph;                                                             \
    }

// Block owns 4 dims; interval-quads (x_i,c_i,x_{i+1},c_{i+1}) staged in LDS
// (4 x 1000 x 16B = 64000B -> still 2 blocks/CU). ONE ds_read_b128 per element
// replaces R2's two ds_read_b64: halves LDS instruction count, address calc,
// and latency events on the per-element critical path (R4 counters: VALU 45%,
// LDS pipe ~25%, rest latency stalls).
// Thread handles 2 dims of one row; lanes 2i/2i+1 -> adjacent 8B chunks =
// 16B/row coalesced; partner-lane shfl sums the 4-dim partial.
template <bool USE_WS>
__global__ __launch_bounds__(BLOCK_THREADS, 8)
void mg_main(const float* __restrict__ x,
             const float* __restrict__ xvals,
             const float* __restrict__ cdf,
             float* __restrict__ out, float* __restrict__ ws, int B) {
    __shared__ float4 quads[DIMS_PER_BLOCK * NBINS];   // 64000 B

    const int dimbase = blockIdx.y * DIMS_PER_BLOCK;

    // stage quads: coalesced scalar reads (tables are L2/L3-resident: 512KB)
#pragma unroll
    for (int d = 0; d < DIMS_PER_BLOCK; ++d) {
        const float* xv = xvals + (size_t)(dimbase + d) * NBINS;
        const float* cv = cdf + (size_t)(dimbase + d) * NBINS;
        for (int i = threadIdx.x; i < NBINS; i += BLOCK_THREADS) {
            int ip = (i < NBINS - 1) ? i + 1 : i;
            quads[d * NBINS + i] = make_float4(xv[i], cv[i], xv[ip], cv[ip]);
        }
    }
    __syncthreads();

    const int dl = (threadIdx.x & 1) * 2;                // local dims dl, dl+1
    const int base0 = dl * NBINS, base1 = base0 + NBINS;
    const int qidx = blockIdx.y * 2 + (threadIdx.x & 1); // float2 index within row

    float scale0, bias0, scale1, bias1;
    {
        float l0 = quads[base0].x, h0 = quads[base0 + NBINS - 2].z;  // x_0, x_999
        float l1 = quads[base1].x, h1 = quads[base1 + NBINS - 2].z;
        scale0 = (float)(NBINS - 1) / (h0 - l0);
        bias0 = -l0 * scale0;
        scale1 = (float)(NBINS - 1) / (h1 - l1);
        bias1 = -l1 * scale1;
    }

    const int rstride = gridDim.x * ROWS_PER_ITER;
    int row = blockIdx.x * ROWS_PER_ITER + (threadIdx.x >> 1);

    float2 xq = make_float2(0.f, 0.f);
    if (row < B) xq = ((const float2*)x)[(size_t)row * (NDIM / 2) + qidx];

    for (; row < B; row += rstride) {
        const int nrow = row + rstride;
        float2 xn = make_float2(0.f, 0.f);
        if (nrow < B) xn = ((const float2*)x)[(size_t)nrow * (NDIM / 2) + qidx];

        int i0 = (int)fmaf(xq.x, scale0, bias0);
        int i1 = (int)fmaf(xq.y, scale1, bias1);
        i0 = min(max(i0, 0), NBINS - 2);
        i1 = min(max(i1, 0), NBINS - 2);
        float4 q0 = quads[base0 + i0];
        float4 q1 = quads[base1 + i1];

        float z0, z1, php = 1.0f, sumsq = 0.0f;
        QDIM_MATH(xq.x, base0, i0, q0, scale0, php, sumsq, z0);
        QDIM_MATH(xq.y, base1, i1, q1, scale1, php, sumsq, z1);

        ((float2*)out)[(size_t)row * (NDIM / 2) + qidx] = make_float2(z0, z1);

        // term = sum_j [log(p_hat_j) + 0.5 z^2 + log(sqrt(2pi))]
        // -log(phi+1e-12) == 0.5 z^2 + 0.9189385 to 4.3e-8 abs since |z|<=4.418
        float term = fmaf(0.5f, sumsq, 2.0f * 0.9189385332046727f) +
                     0.6931471805599453f * __builtin_amdgcn_logf(php);

        term += __shfl_xor(term, 1, 64);   // partner lane covers the other 2 dims
        if ((threadIdx.x & 1) == 0) {
            if constexpr (USE_WS)
                ws[(size_t)blockIdx.y * B + row] = term;   // coalesced partial
            else
                atomicAdd(out + (size_t)B * NDIM + row, term);
        }

        xq = xn;
    }
}

extern "C" void kernel_launch(void* const* d_in, const int* in_sizes, int n_in,
                              void* d_out, int out_size, void* d_ws, size_t ws_size,
                              hipStream_t stream) {
    const float* x = (const float*)d_in[0];
    const float* xvals = (const float*)d_in[1];
    const float* cdf = (const float*)d_in[2];
    float* out = (float*)d_out;
    int B = in_sizes[0] / NDIM;

    const size_t ws_need = (size_t)DIM_GROUPS * B * sizeof(float);
    dim3 grid(ROW_BLOCKS, DIM_GROUPS);

    if (ws_size >= ws_need) {
        float* ws = (float*)d_ws;
        hipLaunchKernelGGL((mg_main<true>), grid, dim3(BLOCK_THREADS), 0, stream,
                           x, xvals, cdf, out, ws, B);
        hipLaunchKernelGGL(mg_reduce, dim3((B + 255) / 256), dim3(256), 0, stream,
                           ws, out + (size_t)B * NDIM, B);
    } else {
        hipLaunchKernelGGL(mg_zero, dim3((B + 1023) / 1024), dim3(1024), 0, stream,
                           out + (size_t)B * NDIM, B);
        hipLaunchKernelGGL((mg_main<false>), grid, dim3(BLOCK_THREADS), 0, stream,
                           x, xvals, cdf, out, (float*)nullptr, B);
    }
}

// Round 6
// 137.997 us; speedup vs baseline: 1.3310x; 1.3310x over previous
//
#include <hip/hip_runtime.h>
#include <math.h>

#define NBINS 1000
#define NDIM 64
#define DIMS_PER_BLOCK 8
#define DIM_GROUPS (NDIM / DIMS_PER_BLOCK)      // 8
#define BLOCK_THREADS 1024
#define ROWS_PER_ITER (BLOCK_THREADS / 2)       // 512 rows per block-iteration
#define ROW_BLOCKS 64                            // 512 blocks = 2/CU, ALL resident
                                                 // (single generation, no turnover).
                                                 // 64%8==0 -> all dim-groups of a row
                                                 // chunk on one XCD (id=x+64y, XCD=
                                                 // id%8=x%8); concurrent working set
                                                 // 8 chunks x 512 rows x 256B = 1MB
                                                 // per XCD L2 -> partial-line merge OK.
                                                 // NEVER shrink per-block row footprint
                                                 // below 32B (R5: 16B -> 3x traffic) or
                                                 // interleave distant rows (R3).

// zero the log_det region (atomic fallback path only)
__global__ __launch_bounds__(1024) void mg_zero(float* __restrict__ p, int n) {
    int i = blockIdx.x * blockDim.x + threadIdx.x;
    if (i < n) p[i] = 0.0f;
}

// final reduce: log_det[row] = sum over 8 dim-group partials in ws
__global__ __launch_bounds__(256) void mg_reduce(const float* __restrict__ ws,
                                                 float* __restrict__ out, int B) {
    int row = blockIdx.x * blockDim.x + threadIdx.x;
    if (row >= B) return;
    float s = 0.0f;
#pragma unroll
    for (int g = 0; g < DIM_GROUPS; ++g) s += ws[(size_t)g * B + row];
    out[row] = s;
}

// per-dim math: exact-fixup + interp + Giles erfinv. MACRO so knots[] stays a
// direct LDS access (no generic-pointer fallout). Updates php/ss, writes zout.
// NOTE: no u-clamp — e1's +-0.99999 clamp subsumes the ref's u in (1e-6,1-1e-6)
// clip exactly (2*1e-6-1 < -0.99999 etc.), bit-identical result.
#define DIM_MATH(xd_, base_, i_, a_, b_, sc_, php_, ss_, zout_)                   \
    {                                                                             \
        float xd = (xd_);                                                         \
        int i = (i_);                                                             \
        float2 a = (a_), b = (b_);                                                \
        if (__builtin_expect((xd > b.x && i < NBINS - 2) ||                       \
                             (xd <= a.x && i > 0), 0)) {                          \
            while (xd > b.x && i < NBINS - 2) {                                   \
                ++i; a = b; b = knots[(base_) + i + 1];                           \
            }                                                                     \
            while (xd <= a.x && i > 0) {                                          \
                --i; b = a; a = knots[(base_) + i];                               \
            }                                                                     \
        }                                                                         \
        float slope = (b.y - a.y) * (sc_);                                        \
        float u = fmaf(slope, xd - a.x, a.y);                                     \
        float ph = fmaxf(slope, 1e-12f);                                          \
        float e1 = fminf(fmaxf(fmaf(2.0f, u, -1.0f), -0.99999f), 0.99999f);       \
        float wv = -0.6931471805599453f *                                         \
                   __builtin_amdgcn_logf(fmaf(-e1, e1, 1.0f));                    \
        float t = wv - 2.5f;                                                      \
        float p = 2.81022636e-08f;                                                \
        p = fmaf(p, t, 3.43273939e-07f);                                          \
        p = fmaf(p, t, -3.5233877e-06f);                                          \
        p = fmaf(p, t, -4.39150654e-06f);                                         \
        p = fmaf(p, t, 0.00021858087f);                                           \
        p = fmaf(p, t, -0.00125372503f);                                          \
        p = fmaf(p, t, -0.00417768164f);                                          \
        p = fmaf(p, t, 0.246640727f);                                             \
        p = fmaf(p, t, 1.50140941f);                                              \
        if (wv >= 5.0f) {                                                         \
            float tq = sqrtf(wv) - 3.0f;                                          \
            float pt = -0.000200214257f;                                          \
            pt = fmaf(pt, tq, 0.000100950558f);                                   \
            pt = fmaf(pt, tq, 0.00134934322f);                                    \
            pt = fmaf(pt, tq, -0.00367342844f);                                   \
            pt = fmaf(pt, tq, 0.00573950773f);                                    \
            pt = fmaf(pt, tq, -0.0076224613f);                                    \
            pt = fmaf(pt, tq, 0.00943887047f);                                    \
            pt = fmaf(pt, tq, 1.00167406f);                                       \
            pt = fmaf(pt, tq, 2.83297682f);                                       \
            p = pt;                                                               \
        }                                                                         \
        float z = 1.4142135623730951f * p * e1; /* |z|<=4.418, ref clamp dead */  \
        (zout_) = z;                                                              \
        (ss_) = fmaf(z, z, (ss_));                                                \
        (php_) *= ph;                                                             \
    }

// lane0<->lane1 pair swap as pure VALU (DPP quad_perm [1,0,3,2] = 0xB1).
// Replaces __shfl_xor's ds_bpermute: NO lgkm event, so the end-of-body reduce
// no longer drains the prefetched next-iteration LDS gathers (R4's 2us bug).
__device__ __forceinline__ float pair_swap_dpp(float v) {
    return __int_as_float(__builtin_amdgcn_update_dpp(
        __float_as_int(v), __float_as_int(v), 0xB1, 0xF, 0xF, true));
}

// Block owns 8 dims; knots (x_i,c_i) staged in LDS (64 KB).
// MEMORY STRUCTURE = R2/R4 (measured best: FETCH ~66MB, WRITE ~87MB).
// Pipeline per body k: issue x(k+2) -> math(k) [gathers issued in body k-1,
// lgkm wait has a full body of slack] -> bins+gathers(k+1) from x(k+1)
// [arrived: issued 2 bodies ago] -> stores + DPP reduce [no lgkm wait].
template <bool USE_WS>
__global__ __launch_bounds__(BLOCK_THREADS, 8)
void mg_main(const float* __restrict__ x,
             const float* __restrict__ xvals,
             const float* __restrict__ cdf,
             float* __restrict__ out, float* __restrict__ ws, int B) {
    __shared__ float2 knots[DIMS_PER_BLOCK * NBINS];   // 64000 B

    const int dimbase = blockIdx.y * DIMS_PER_BLOCK;

    {   // vectorized stage: 2000 float4s from each table
        const float4* xv4 = (const float4*)(xvals + (size_t)dimbase * NBINS);
        const float4* cd4 = (const float4*)(cdf + (size_t)dimbase * NBINS);
        for (int k = threadIdx.x; k < DIMS_PER_BLOCK * NBINS / 4; k += BLOCK_THREADS) {
            float4 a = xv4[k], c = cd4[k];
            knots[k * 4 + 0] = make_float2(a.x, c.x);
            knots[k * 4 + 1] = make_float2(a.y, c.y);
            knots[k * 4 + 2] = make_float2(a.z, c.z);
            knots[k * 4 + 3] = make_float2(a.w, c.w);
        }
    }
    __syncthreads();

    const int dl = (threadIdx.x & 1) * 4;                // local dims dl..dl+3
    const int qidx = blockIdx.y * 2 + (threadIdx.x & 1); // float4 index within row

    float scale[4], bias[4];
#pragma unroll
    for (int j = 0; j < 4; ++j) {
        float l = knots[(dl + j) * NBINS].x;
        float h = knots[(dl + j) * NBINS + NBINS - 1].x;
        float s = (float)(NBINS - 1) / (h - l);          // == 1/step_d
        scale[j] = s;
        bias[j] = -l * s;
    }

    const int rstride = gridDim.x * ROWS_PER_ITER;
    int row = blockIdx.x * ROWS_PER_ITER + (threadIdx.x >> 1);

    // prologue: x for iter 0 and 1; bins+gathers for iter 0
    float4 xq = make_float4(0.f, 0.f, 0.f, 0.f);
    float4 xn = make_float4(0.f, 0.f, 0.f, 0.f);
    if (row < B) xq = ((const float4*)x)[(size_t)row * (NDIM / 4) + qidx];
    if (row + rstride < B)
        xn = ((const float4*)x)[(size_t)(row + rstride) * (NDIM / 4) + qidx];

    int ii[4];
    float2 kl[4], kr[4];
    {
        float xv[4] = {xq.x, xq.y, xq.z, xq.w};
#pragma unroll
        for (int j = 0; j < 4; ++j) {
            int i = (int)fmaf(xv[j], scale[j], bias[j]);
            ii[j] = min(max(i, 0), NBINS - 2);
        }
#pragma unroll
        for (int j = 0; j < 4; ++j) {
            kl[j] = knots[(dl + j) * NBINS + ii[j]];
            kr[j] = knots[(dl + j) * NBINS + ii[j] + 1];
        }
    }

    for (; row < B; row += rstride) {
        // issue x(k+2): consumed by bins+gathers two bodies from now
        const int prow = row + 2 * rstride;
        float4 xn2 = make_float4(0.f, 0.f, 0.f, 0.f);
        if (prow < B) xn2 = ((const float4*)x)[(size_t)prow * (NDIM / 4) + qidx];

        // math on current row: gathers issued LAST body, full body of slack
        float z4[4], php = 1.0f, sumsq = 0.0f;
        DIM_MATH(xq.x, (dl + 0) * NBINS, ii[0], kl[0], kr[0], scale[0],
                 php, sumsq, z4[0]);
        DIM_MATH(xq.y, (dl + 1) * NBINS, ii[1], kl[1], kr[1], scale[1],
                 php, sumsq, z4[1]);
        DIM_MATH(xq.z, (dl + 2) * NBINS, ii[2], kl[2], kr[2], scale[2],
                 php, sumsq, z4[2]);
        DIM_MATH(xq.w, (dl + 3) * NBINS, ii[3], kl[3], kr[3], scale[3],
                 php, sumsq, z4[3]);

        // bins + gathers for NEXT body from xn (loaded 2 bodies ago, no vm wait)
        {
            float xv[4] = {xn.x, xn.y, xn.z, xn.w};
#pragma unroll
            for (int j = 0; j < 4; ++j) {
                int i = (int)fmaf(xv[j], scale[j], bias[j]);
                ii[j] = min(max(i, 0), NBINS - 2);   // safe even for dummy xn=0
            }
#pragma unroll
            for (int j = 0; j < 4; ++j) {
                kl[j] = knots[(dl + j) * NBINS + ii[j]];
                kr[j] = knots[(dl + j) * NBINS + ii[j] + 1];
            }
        }

        ((float4*)out)[(size_t)row * (NDIM / 4) + qidx] =
            make_float4(z4[0], z4[1], z4[2], z4[3]);

        // term = sum_j [log(p_hat_j) + 0.5 z^2 + log(sqrt(2pi))]
        // -log(phi+1e-12) == 0.5 z^2 + 0.9189385 to 4.3e-8 abs since |z|<=4.418
        float term = fmaf(0.5f, sumsq, 4.0f * 0.9189385332046727f) +
                     0.6931471805599453f * __builtin_amdgcn_logf(php);

        term += pair_swap_dpp(term);       // partner lane covers the other 4 dims
        if ((threadIdx.x & 1) == 0) {
            if constexpr (USE_WS)
                ws[(size_t)blockIdx.y * B + row] = term;   // coalesced partial
            else
                atomicAdd(out + (size_t)B * NDIM + row, term);
        }

        xq = xn;
        xn = xn2;
    }
}

extern "C" void kernel_launch(void* const* d_in, const int* in_sizes, int n_in,
                              void* d_out, int out_size, void* d_ws, size_t ws_size,
                              hipStream_t stream) {
    const float* x = (const float*)d_in[0];
    const float* xvals = (const float*)d_in[1];
    const float* cdf = (const float*)d_in[2];
    float* out = (float*)d_out;
    int B = in_sizes[0] / NDIM;

    const size_t ws_need = (size_t)DIM_GROUPS * B * sizeof(float);
    dim3 grid(ROW_BLOCKS, DIM_GROUPS);

    if (ws_size >= ws_need) {
        float* ws = (float*)d_ws;
        hipLaunchKernelGGL((mg_main<true>), grid, dim3(BLOCK_THREADS), 0, stream,
                           x, xvals, cdf, out, ws, B);
        hipLaunchKernelGGL(mg_reduce, dim3((B + 255) / 256), dim3(256), 0, stream,
                           ws, out + (size_t)B * NDIM, B);
    } else {
        hipLaunchKernelGGL(mg_zero, dim3((B + 1023) / 1024), dim3(1024), 0, stream,
                           out + (size_t)B * NDIM, B);
        hipLaunchKernelGGL((mg_main<false>), grid, dim3(BLOCK_THREADS), 0, stream,
                           x, xvals, cdf, out, (float*)nullptr, B);
    }
}